// Round 5
// baseline (135.318 us; speedup 1.0000x reference)
//
#include <hip/hip_runtime.h>

#define NPTS 4096
#define KNN  16
#define K1   17          // KNN + self
#define BLK  512
#define WPB  8           // waves per block, one (sorted-position) query per wave
#define BPB  (NPTS / WPB)  // 512 main blocks per batch
#define EPSF 1e-10f

__device__ __forceinline__ unsigned umin_(unsigned a, unsigned b) { return a < b ? a : b; }
__device__ __forceinline__ unsigned umax_(unsigned a, unsigned b) { return a < b ? b : a; }

__device__ __forceinline__ unsigned part1by2(unsigned x) {
    x &= 0x3FFu;
    x = (x | (x << 16)) & 0x030000FFu;
    x = (x | (x << 8))  & 0x0300F00Fu;
    x = (x | (x << 4))  & 0x030C30C3u;
    x = (x | (x << 2))  & 0x09249249u;
    return x;
}

// ---- Kernel 1: per-batch Morton sort of ref points (permutation only ->
// any bug here costs speed, not correctness). key = morton18<<12 | idx.
__global__ __launch_bounds__(1024) void sort_kernel(
    const float* __restrict__ pref,
    float2* __restrict__ wxy, float* __restrict__ wz, int* __restrict__ widx)
{
    __shared__ float sx[NPTS], sy[NPTS], sz[NPTS];   // 48 KB
    __shared__ unsigned skey[NPTS];                   // 16 KB
    const int b = blockIdx.x;
    const float* prb = pref + (size_t)b * NPTS * 3;

    for (int p = threadIdx.x; p < NPTS; p += 1024) {
        float x = prb[3 * p + 0], y = prb[3 * p + 1], z = prb[3 * p + 2];
        sx[p] = x; sy[p] = y; sz[p] = z;
        int qx = min(63, max(0, (int)((x + 4.0f) * 8.0f)));
        int qy = min(63, max(0, (int)((y + 4.0f) * 8.0f)));
        int qz = min(63, max(0, (int)((z + 4.0f) * 8.0f)));
        unsigned m = part1by2((unsigned)qx) | (part1by2((unsigned)qy) << 1)
                   | (part1by2((unsigned)qz) << 2);
        skey[p] = (m << 12) | (unsigned)p;
    }
    __syncthreads();

    for (unsigned k = 2; k <= NPTS; k <<= 1) {
        for (unsigned j = k >> 1; j > 0; j >>= 1) {
            for (unsigned t = threadIdx.x; t < NPTS / 2; t += 1024) {
                unsigned e = 2u * t - (t & (j - 1u));   // bit j of e is clear
                unsigned f = e | j;
                unsigned a = skey[e], c = skey[f];
                if ((a > c) == ((e & k) == 0u)) { skey[e] = c; skey[f] = a; }
            }
            __syncthreads();
        }
    }

    const size_t base = (size_t)b * NPTS;
    for (int p = threadIdx.x; p < NPTS; p += 1024) {
        unsigned i = skey[p] & 0xFFFu;
        wxy[base + p]  = make_float2(sx[i], sy[i]);
        wz[base + p]   = sz[i];
        widx[base + p] = (int)i;
    }
}

// ---- Kernel 2: one wave per sorted-position query; scan own 64-block first
// (bootstrap bitonic), then remaining blocks cyclically. Lane-sliced sorted
// top-17 packed keys (d2 hi-20 bits | sorted-pos 12 bits); self d2 == +0.0
// exactly -> key = p = minimum.
#define SCAN_BATCH(jb) do {                                                   \
    int j_ = (jb) + lane;                                                     \
    float2 c_ = xy[j_];                                                       \
    float cz_ = zz[j_];                                                       \
    float dx_ = c_.x - qx, dy_ = c_.y - qy, dz_ = cz_ - qz;                   \
    float d2_ = dx_ * dx_ + dy_ * dy_ + dz_ * dz_;                            \
    unsigned key_ = (__float_as_uint(d2_) & 0xFFFFF000u) | (unsigned)j_;      \
    unsigned long long m_ = __ballot(key_ < thr);                             \
    if (m_) {                                                                 \
        do {                                                                  \
            int l_ = __ffsll(m_) - 1;                                         \
            m_ &= m_ - 1;                                                     \
            unsigned kk_ = (unsigned)__builtin_amdgcn_readlane((int)key_, l_);\
            unsigned long long lt_ = __ballot(arr < kk_) & 0x1FFFFull;        \
            int pos_ = __popcll(lt_);                                         \
            unsigned up_ = __shfl_up(arr, 1);                                 \
            arr = (lane == pos_) ? kk_ : ((lane > pos_) ? up_ : arr);         \
        } while (m_);                                                         \
        thr = (unsigned)__builtin_amdgcn_readlane((int)arr, K1 - 1);          \
    } } while (0)

__global__ __launch_bounds__(BLK, 6) void knn_main_kernel(
    const float* __restrict__ ppred,
    const float2* __restrict__ wxy, const float* __restrict__ wz,
    const int* __restrict__ widx, float* __restrict__ partials)
{
    __shared__ float2 xy[NPTS];   // 32 KB
    __shared__ float  zz[NPTS];   // 16 KB
    __shared__ float  wsum[WPB];

    const int w    = threadIdx.x >> 6;
    const int lane = threadIdx.x & 63;
    const int b    = blockIdx.x / BPB;
    const int p    = (blockIdx.x % BPB) * WPB + w;   // sorted position = query
    const size_t base = (size_t)b * NPTS;

    for (int t = threadIdx.x; t < NPTS; t += BLK) {
        xy[t] = wxy[base + t];
        zz[t] = wz[base + t];
    }
    __syncthreads();

    const float2 qv = xy[p];
    const float qx = qv.x, qy = qv.y, qz = zz[p];
    const int p0 = p & ~63;

    // Bootstrap: bitonic sort of own 64-block (contains self at d2 = 0).
    unsigned arr;
    {
        int j = p0 + lane;
        float2 c = xy[j];
        float dx = c.x - qx, dy = c.y - qy, dz = zz[j] - qz;
        float d2 = dx * dx + dy * dy + dz * dz;
        arr = (__float_as_uint(d2) & 0xFFFFF000u) | (unsigned)j;
    }
#pragma unroll
    for (int k = 2; k <= 64; k <<= 1) {
#pragma unroll
        for (int j = k >> 1; j > 0; j >>= 1) {
            unsigned other = __shfl_xor(arr, j);
            bool takeMin = (((lane & j) == 0) == ((lane & k) == 0));
            unsigned mn = umin_(arr, other), mx = umax_(arr, other);
            arr = takeMin ? mn : mx;
        }
    }
    unsigned thr = (unsigned)__builtin_amdgcn_readlane((int)arr, K1 - 1);

    // Scan all other blocks, spatially-near ones first (no wrap arithmetic).
    for (int jb = p0 + 64; jb < NPTS; jb += 64) SCAN_BATCH(jb);
    for (int jb = 0; jb < p0; jb += 64) SCAN_BATCH(jb);

    // Epilogue: lanes 1..16 hold the 16 nearest neighbors (lane 0 = self).
    const float* ppb = ppred + (size_t)b * NPTS * 3;
    const int iorig = widx[base + p];   // uniform address -> broadcast
    float s = 0.f;
    if (lane >= 1 && lane <= KNN) {
        int js = (int)(arr & 0xFFFu);
        float2 rc = xy[js];
        float rx = rc.x - qx, ry = rc.y - qy, rz = zz[js] - qz;
        float dref = sqrtf(rx * rx + ry * ry + rz * rz);
        int nj = widx[base + js];
        float px = ppb[3 * iorig + 0], py = ppb[3 * iorig + 1], pz = ppb[3 * iorig + 2];
        float ax = ppb[3 * nj + 0] - px;
        float ay = ppb[3 * nj + 1] - py;
        float az = ppb[3 * nj + 2] - pz;
        float dpred = sqrtf(ax * ax + ay * ay + az * az);
        s = fmaxf(dpred / (dref + EPSF) - 1.0f, 0.0f);
    }
    for (int off = 32; off > 0; off >>= 1) s += __shfl_down(s, off);
    if (lane == 0) wsum[w] = s;
    __syncthreads();
    if (threadIdx.x == 0) {
        float t = 0.f;
#pragma unroll
        for (int k = 0; k < WPB; ++k) t += wsum[k];
        partials[blockIdx.x] = t;
    }
}

// ---- Kernel 3: deterministic single-block final reduction.
__global__ __launch_bounds__(256) void reduce_kernel(
    const float* __restrict__ partials, int n, float* __restrict__ out, float scale)
{
    __shared__ float wsum[4];
    float s = 0.f;
    for (int idx = threadIdx.x; idx < n; idx += 256) s += partials[idx];
    for (int off = 32; off > 0; off >>= 1) s += __shfl_down(s, off);
    if ((threadIdx.x & 63) == 0) wsum[threadIdx.x >> 6] = s;
    __syncthreads();
    if (threadIdx.x == 0)
        out[0] = ((wsum[0] + wsum[1]) + (wsum[2] + wsum[3])) * scale;
}

extern "C" void kernel_launch(void* const* d_in, const int* in_sizes, int n_in,
                              void* d_out, int out_size, void* d_ws, size_t ws_size,
                              hipStream_t stream) {
    const float* pref  = (const float*)d_in[0];
    const float* ppred = (const float*)d_in[1];
    float* out = (float*)d_out;

    const int B = in_sizes[0] / (NPTS * 3);
    const int nblocks = B * BPB;
    const float scale = 1.0f / ((float)B * (float)NPTS * (float)KNN);

    char* ws = (char*)d_ws;
    float2* wxy  = (float2*)ws;                                  // B*N*8 bytes
    float*  wz   = (float*)(ws + (size_t)B * NPTS * 8);          // B*N*4
    int*    widx = (int*)  (ws + (size_t)B * NPTS * 12);         // B*N*4
    float*  partials = (float*)(ws + (size_t)B * NPTS * 16);     // nblocks*4

    sort_kernel<<<dim3(B), dim3(1024), 0, stream>>>(pref, wxy, wz, widx);
    knn_main_kernel<<<dim3(nblocks), dim3(BLK), 0, stream>>>(ppred, wxy, wz, widx, partials);
    reduce_kernel<<<dim3(1), dim3(256), 0, stream>>>(partials, nblocks, out, scale);
}

// Round 6
// 98.219 us; speedup vs baseline: 1.3777x; 1.3777x over previous
//
#include <hip/hip_runtime.h>

#define NPTS 4096
#define KNN  16
#define K1   17            // KNN + self
#define BLK  1024
#define WPB  16            // waves per block, one (sorted-position) query per wave
#define BPB  (NPTS / WPB)  // 256 main blocks per batch
#define EPSF 1e-10f

__device__ __forceinline__ unsigned umin_(unsigned a, unsigned b) { return a < b ? a : b; }
__device__ __forceinline__ unsigned umax_(unsigned a, unsigned b) { return a < b ? b : a; }

// spread 3 bits to positions 0,3,6
__device__ __forceinline__ unsigned m3(unsigned x) {
    return (x & 1u) | ((x & 2u) << 2) | ((x & 4u) << 4);
}

// ---- Kernel 1: per-batch counting sort by 9-bit Morton cell (8x8x8 over
// [-4,4]^3). Permutation-only -> exactness never depends on this kernel.
__global__ __launch_bounds__(1024) void sort_kernel(
    const float* __restrict__ pref,
    float2* __restrict__ wxy, float* __restrict__ wz, int* __restrict__ widx)
{
    __shared__ unsigned hist[512];
    __shared__ unsigned short cells[NPTS];   // 8 KB
    const int b = blockIdx.x;
    const float* prb = pref + (size_t)b * NPTS * 3;
    const size_t base = (size_t)b * NPTS;

    if (threadIdx.x < 512) hist[threadIdx.x] = 0;
    __syncthreads();

    for (int p = threadIdx.x; p < NPTS; p += 1024) {
        float x = prb[3 * p + 0], y = prb[3 * p + 1], z = prb[3 * p + 2];
        int qx = min(7, max(0, (int)(x + 4.0f)));
        int qy = min(7, max(0, (int)(y + 4.0f)));
        int qz = min(7, max(0, (int)(z + 4.0f)));
        unsigned c = m3((unsigned)qx) | (m3((unsigned)qy) << 1) | (m3((unsigned)qz) << 2);
        cells[p] = (unsigned short)c;
        atomicAdd(&hist[c], 1u);
    }
    __syncthreads();

    // Exclusive prefix scan of hist[512] by wave 0 (8 cells per lane).
    if (threadIdx.x < 64) {
        const int lane = threadIdx.x;
        unsigned loc[8], sum = 0;
#pragma unroll
        for (int k = 0; k < 8; ++k) { loc[k] = hist[lane * 8 + k]; sum += loc[k]; }
        unsigned run = sum;
#pragma unroll
        for (int d = 1; d < 64; d <<= 1) {
            unsigned o = __shfl_up(run, d);
            if (lane >= d) run += o;
        }
        unsigned excl = run - sum;
#pragma unroll
        for (int k = 0; k < 8; ++k) { hist[lane * 8 + k] = excl; excl += loc[k]; }
    }
    __syncthreads();

    for (int p = threadIdx.x; p < NPTS; p += 1024) {
        unsigned c = cells[p];
        unsigned pos = atomicAdd(&hist[c], 1u);
        wxy[base + pos]  = make_float2(prb[3 * p + 0], prb[3 * p + 1]);
        wz[base + pos]   = prb[3 * p + 2];
        widx[base + pos] = p;
    }
}

// ---- Kernel 2: one wave per sorted-position query. Lane-sliced sorted
// top-17 packed keys (d2 hi-20 | sorted-pos 12); self d2 == +0.0 -> minimum.
#define EVENTS(KEY) do {                                                      \
    unsigned long long m_ = __ballot((KEY) < thr);                            \
    if (m_) {                                                                 \
        do {                                                                  \
            int l_ = __ffsll(m_) - 1;                                         \
            m_ &= m_ - 1;                                                     \
            unsigned kk_ = (unsigned)__builtin_amdgcn_readlane((int)(KEY), l_);\
            unsigned long long lt_ = __ballot(arr < kk_) & 0x1FFFFull;        \
            int pos_ = __popcll(lt_);                                         \
            unsigned up_ = __shfl_up(arr, 1);                                 \
            arr = (lane == pos_) ? kk_ : ((lane > pos_) ? up_ : arr);         \
        } while (m_);                                                         \
        thr = (unsigned)__builtin_amdgcn_readlane((int)arr, K1 - 1);          \
    } } while (0)

#define SCAN1(OFF) do {                                                       \
    int j_ = ((p0 + (OFF)) & (NPTS - 1)) + lane;                              \
    float2 a_ = xy[j_]; float z_ = zz[j_];                                    \
    float dx_ = a_.x - qx, dy_ = a_.y - qy, dz_ = z_ - qz;                    \
    float d2_ = dx_ * dx_ + dy_ * dy_ + dz_ * dz_;                            \
    unsigned k_ = (__float_as_uint(d2_) & 0xFFFFF000u) | (unsigned)j_;        \
    EVENTS(k_); } while (0)

#define SCAN4(OFF) do {                                                       \
    int j0_ = ((p0 + (OFF))       & (NPTS - 1)) + lane;                       \
    int j1_ = ((p0 + (OFF) + 64)  & (NPTS - 1)) + lane;                       \
    int j2_ = ((p0 + (OFF) + 128) & (NPTS - 1)) + lane;                       \
    int j3_ = ((p0 + (OFF) + 192) & (NPTS - 1)) + lane;                       \
    float2 a0_ = xy[j0_], a1_ = xy[j1_], a2_ = xy[j2_], a3_ = xy[j3_];        \
    float z0_ = zz[j0_], z1_ = zz[j1_], z2_ = zz[j2_], z3_ = zz[j3_];         \
    float dx_, dy_, dz_;                                                      \
    dx_ = a0_.x - qx; dy_ = a0_.y - qy; dz_ = z0_ - qz;                       \
    float d20_ = dx_ * dx_ + dy_ * dy_ + dz_ * dz_;                           \
    dx_ = a1_.x - qx; dy_ = a1_.y - qy; dz_ = z1_ - qz;                       \
    float d21_ = dx_ * dx_ + dy_ * dy_ + dz_ * dz_;                           \
    dx_ = a2_.x - qx; dy_ = a2_.y - qy; dz_ = z2_ - qz;                       \
    float d22_ = dx_ * dx_ + dy_ * dy_ + dz_ * dz_;                           \
    dx_ = a3_.x - qx; dy_ = a3_.y - qy; dz_ = z3_ - qz;                       \
    float d23_ = dx_ * dx_ + dy_ * dy_ + dz_ * dz_;                           \
    unsigned k0_ = (__float_as_uint(d20_) & 0xFFFFF000u) | (unsigned)j0_;     \
    unsigned k1_ = (__float_as_uint(d21_) & 0xFFFFF000u) | (unsigned)j1_;     \
    unsigned k2_ = (__float_as_uint(d22_) & 0xFFFFF000u) | (unsigned)j2_;     \
    unsigned k3_ = (__float_as_uint(d23_) & 0xFFFFF000u) | (unsigned)j3_;     \
    bool hit_ = (k0_ < thr) | (k1_ < thr) | (k2_ < thr) | (k3_ < thr);        \
    if (__any(hit_)) { EVENTS(k0_); EVENTS(k1_); EVENTS(k2_); EVENTS(k3_); }  \
    } while (0)

__global__ __launch_bounds__(BLK, 8) void knn_main_kernel(
    const float* __restrict__ ppred,
    const float2* __restrict__ wxy, const float* __restrict__ wz,
    const int* __restrict__ widx, float* __restrict__ partials)
{
    __shared__ float2 xy[NPTS];   // 32 KB
    __shared__ float  zz[NPTS];   // 16 KB
    __shared__ float  wsum[WPB];

    const int w    = threadIdx.x >> 6;
    const int lane = threadIdx.x & 63;
    const int b    = blockIdx.x / BPB;
    const int p    = (blockIdx.x % BPB) * WPB + w;   // sorted position = query
    const size_t base = (size_t)b * NPTS;

    for (int t = threadIdx.x; t < NPTS; t += BLK) {
        xy[t] = wxy[base + t];
        zz[t] = wz[base + t];
    }
    __syncthreads();

    const float2 qv = xy[p];
    const float qx = qv.x, qy = qv.y, qz = zz[p];
    const int p0 = p & ~63;

    // Bootstrap: bitonic sort of own 64-block (contains self at d2 = 0).
    unsigned arr;
    {
        int j = p0 + lane;
        float2 c = xy[j];
        float dx = c.x - qx, dy = c.y - qy, dz = zz[j] - qz;
        float d2 = dx * dx + dy * dy + dz * dz;
        arr = (__float_as_uint(d2) & 0xFFFFF000u) | (unsigned)j;
    }
#pragma unroll
    for (int k = 2; k <= 64; k <<= 1) {
#pragma unroll
        for (int j = k >> 1; j > 0; j >>= 1) {
            unsigned other = __shfl_xor(arr, j);
            bool takeMin = (((lane & j) == 0) == ((lane & k) == 0));
            unsigned mn = umin_(arr, other), mx = umax_(arr, other);
            arr = takeMin ? mn : mx;
        }
    }
    unsigned thr = (unsigned)__builtin_amdgcn_readlane((int)arr, K1 - 1);

    // Scan remaining 63 batches cyclically, spatially-near first.
    int off = 64;
#pragma unroll 1
    for (; off + 192 < NPTS; off += 256) SCAN4(off);
#pragma unroll 1
    for (; off < NPTS; off += 64) SCAN1(off);

    // Epilogue: lanes 1..16 hold the 16 nearest neighbors (lane 0 = self).
    const float* ppb = ppred + (size_t)b * NPTS * 3;
    const int iorig = widx[base + p];   // uniform -> broadcast
    float s = 0.f;
    if (lane >= 1 && lane <= KNN) {
        int js = (int)(arr & 0xFFFu);
        float2 rc = xy[js];
        float rx = rc.x - qx, ry = rc.y - qy, rz = zz[js] - qz;
        float dref = sqrtf(rx * rx + ry * ry + rz * rz);
        int nj = widx[base + js];
        float px = ppb[3 * iorig + 0], py = ppb[3 * iorig + 1], pz = ppb[3 * iorig + 2];
        float ax = ppb[3 * nj + 0] - px;
        float ay = ppb[3 * nj + 1] - py;
        float az = ppb[3 * nj + 2] - pz;
        float dpred = sqrtf(ax * ax + ay * ay + az * az);
        s = fmaxf(dpred / (dref + EPSF) - 1.0f, 0.0f);
    }
    for (int offr = 32; offr > 0; offr >>= 1) s += __shfl_down(s, offr);
    if (lane == 0) wsum[w] = s;
    __syncthreads();
    if (threadIdx.x == 0) {
        float t = 0.f;
#pragma unroll
        for (int k = 0; k < WPB; ++k) t += wsum[k];
        partials[blockIdx.x] = t;
    }
}

// ---- Kernel 3: deterministic single-block final reduction.
__global__ __launch_bounds__(256) void reduce_kernel(
    const float* __restrict__ partials, int n, float* __restrict__ out, float scale)
{
    __shared__ float wsum[4];
    float s = 0.f;
    for (int idx = threadIdx.x; idx < n; idx += 256) s += partials[idx];
    for (int off = 32; off > 0; off >>= 1) s += __shfl_down(s, off);
    if ((threadIdx.x & 63) == 0) wsum[threadIdx.x >> 6] = s;
    __syncthreads();
    if (threadIdx.x == 0)
        out[0] = ((wsum[0] + wsum[1]) + (wsum[2] + wsum[3])) * scale;
}

extern "C" void kernel_launch(void* const* d_in, const int* in_sizes, int n_in,
                              void* d_out, int out_size, void* d_ws, size_t ws_size,
                              hipStream_t stream) {
    const float* pref  = (const float*)d_in[0];
    const float* ppred = (const float*)d_in[1];
    float* out = (float*)d_out;

    const int B = in_sizes[0] / (NPTS * 3);
    const int nblocks = B * BPB;
    const float scale = 1.0f / ((float)B * (float)NPTS * (float)KNN);

    char* ws = (char*)d_ws;
    float2* wxy  = (float2*)ws;                                  // B*N*8 bytes
    float*  wz   = (float*)(ws + (size_t)B * NPTS * 8);          // B*N*4
    int*    widx = (int*)  (ws + (size_t)B * NPTS * 12);         // B*N*4
    float*  partials = (float*)(ws + (size_t)B * NPTS * 16);     // nblocks*4

    sort_kernel<<<dim3(B), dim3(1024), 0, stream>>>(pref, wxy, wz, widx);
    knn_main_kernel<<<dim3(nblocks), dim3(BLK), 0, stream>>>(ppred, wxy, wz, widx, partials);
    reduce_kernel<<<dim3(1), dim3(256), 0, stream>>>(partials, nblocks, out, scale);
}